// Round 1
// baseline (462.505 us; speedup 1.0000x reference)
//
#include <hip/hip_runtime.h>

typedef __attribute__((ext_vector_type(8))) short bf16x8;
typedef __attribute__((ext_vector_type(4))) float f32x4;

#define NEG_BIG (-4294967295.0f)

// RNE float->bf16 (values are finite; no NaN handling needed)
__device__ __forceinline__ unsigned short f2b(float f) {
  union { float f; unsigned u; } a; a.f = f;
  unsigned r = a.u + 0x7FFFu + ((a.u >> 16) & 1u);
  return (unsigned short)(r >> 16);
}

__device__ __forceinline__ bf16x8 pack8(float4 a, float4 b) {
  bf16x8 r;
  r[0] = (short)f2b(a.x); r[1] = (short)f2b(a.y);
  r[2] = (short)f2b(a.z); r[3] = (short)f2b(a.w);
  r[4] = (short)f2b(b.x); r[5] = (short)f2b(b.y);
  r[6] = (short)f2b(b.z); r[7] = (short)f2b(b.w);
  return r;
}

// Fold W1 [256][80] into:
//   w1qT[j][i] = W1a[i][j] + W1c[i][j]    (q-projection weights, fp32, [80][64])
//   wkT [j][i] = W1b[i][j] - W1c[i][j]    (k weights, fp32, [80][64])
//   wdT [j][i] = W1d[i][j]                (q*k weights, fp32, [80][64])
// and W2 [80][40] into transposed zero-padded bf16 w2t[48][104] (N pad to 48, K pad to 96+8).
__global__ void prep_kernel(const float* __restrict__ W1, const float* __restrict__ W2,
                            float* __restrict__ w1qT, float* __restrict__ wkT,
                            float* __restrict__ wdT, unsigned short* __restrict__ w2t) {
  int tid = blockIdx.x * blockDim.x + threadIdx.x;
  int nthr = gridDim.x * blockDim.x;
  for (int idx = tid; idx < 80 * 64; idx += nthr) {
    int j = idx >> 6, i = idx & 63;
    float a = W1[i * 80 + j];
    float b = W1[(64 + i) * 80 + j];
    float c = W1[(128 + i) * 80 + j];
    float d = W1[(192 + i) * 80 + j];
    w1qT[idx] = a + c;
    wkT[idx]  = b - c;
    wdT[idx]  = d;
  }
  for (int idx = tid; idx < 48 * 104; idx += nthr) {
    int g = idx / 104, j = idx % 104;
    float val = (g < 40 && j < 80) ? W2[j * 40 + g] : 0.0f;
    w2t[idx] = f2b(val);
  }
}

// One block per batch row b. 256 threads = 4 waves.
__global__ __launch_bounds__(256, 2)
void din_kernel(const float* __restrict__ q, const float* __restrict__ k,
                const float* __restrict__ v, const int* __restrict__ mask,
                const float* __restrict__ b1, const float* __restrict__ b2,
                const float* __restrict__ Wf, const float* __restrict__ bfp,
                const float* __restrict__ w1qT, const float* __restrict__ wkT,
                const float* __restrict__ wdT, const unsigned short* __restrict__ w2t,
                float* __restrict__ out) {
  const int b = blockIdx.x;
  const int tid = threadIdx.x;
  const int lane = tid & 63;
  const int wave = tid >> 6;
  const int cq = lane & 15;   // A-row / B-col / C-col within tile
  const int kg = lane >> 4;   // k-group (0..3), 8 consecutive k each

  // bf16 LDS tiles, row strides chosen: multiples of 16 B, bank-shift per row
  // gives <=2-way conflicts (free) for ds_read_b128 fragment loads.
  __shared__ unsigned short wq_l[80][72];    // B1: [col j][k i], stride 144 B
  __shared__ unsigned short h1_l[208][104];  // A2: [row t][k j], stride 208 B
  __shared__ unsigned short w2_l[48][104];   // B2: [col g][k j], stride 208 B
  __shared__ float ql[64];
  __shared__ float qpb[80];   // qproj + b1
  __shared__ float b2l[40];
  __shared__ float wfl[40];
  __shared__ float sco[208];
  __shared__ float att[208];
  __shared__ float red[8];
  __shared__ float op[4][64];

  // ---------------- phase 0: small staging ----------------
  if (tid < 64) ql[tid] = q[b * 64 + tid];
  if (tid >= 64 && tid < 104) b2l[tid - 64] = b2[tid - 64];
  if (tid >= 104 && tid < 144) wfl[tid - 104] = Wf[tid - 104];
  {
    const uint4* src = (const uint4*)w2t;
    uint4* dst = (uint4*)&w2_l[0][0];
    for (int i = tid; i < 624; i += 256) dst[i] = src[i];   // 48*104*2/16
  }
  // zero h1 pad regions so GEMM2's padded K/M reads are NaN-safe:
  //   cols 80..103 for all 208 rows, rows 200..207 cols 0..79
  for (int i = tid; i < 208 * 3; i += 256) {
    int r = i / 3, c = 80 + (i % 3) * 8;
    *(uint4*)&h1_l[r][c] = make_uint4(0u, 0u, 0u, 0u);
  }
  if (tid < 80) {
    int r = 200 + tid / 10, c = (tid % 10) * 8;
    *(uint4*)&h1_l[r][c] = make_uint4(0u, 0u, 0u, 0u);
  }
  __syncthreads();

  // ---------------- phase 1: build Wq (bf16) + qproj (fp32) ----------------
  for (int g = tid; g < 640; g += 256) {          // 80 cols x 8 k-groups
    int j = g >> 3, i0 = (g & 7) << 3;
    const float4* pk = (const float4*)&wkT[j * 64 + i0];
    const float4* pd = (const float4*)&wdT[j * 64 + i0];
    float4 k0 = pk[0], k1 = pk[1], d0 = pd[0], d1 = pd[1];
    bf16x8 o;
    o[0] = (short)f2b(k0.x + ql[i0 + 0] * d0.x);
    o[1] = (short)f2b(k0.y + ql[i0 + 1] * d0.y);
    o[2] = (short)f2b(k0.z + ql[i0 + 2] * d0.z);
    o[3] = (short)f2b(k0.w + ql[i0 + 3] * d0.w);
    o[4] = (short)f2b(k1.x + ql[i0 + 4] * d1.x);
    o[5] = (short)f2b(k1.y + ql[i0 + 5] * d1.y);
    o[6] = (short)f2b(k1.z + ql[i0 + 6] * d1.z);
    o[7] = (short)f2b(k1.w + ql[i0 + 7] * d1.w);
    *(bf16x8*)&wq_l[j][i0] = o;
  }
  if (tid < 80) {
    const float4* wr = (const float4*)&w1qT[tid * 64];
    float s = b1[tid];
    for (int i = 0; i < 16; i++) {
      float4 w4 = wr[i];
      s += ql[4 * i] * w4.x + ql[4 * i + 1] * w4.y +
           ql[4 * i + 2] * w4.z + ql[4 * i + 3] * w4.w;
    }
    qpb[tid] = s;
  }
  __syncthreads();

  // ---------------- GEMM1: h1[200][80] = relu(k[200][64] @ Wq + qproj) ----------------
  // A-fragments come straight from global (each k element read exactly once).
  for (int mt = wave; mt < 13; mt += 4) {
    int trow = mt * 16 + cq;
    bf16x8 afr0, afr1;
    if (trow < 200) {
      const float* kp = k + ((long)b * 200 + trow) * 64 + kg * 8;
      float4 f00 = *(const float4*)(kp);
      float4 f01 = *(const float4*)(kp + 4);
      float4 f10 = *(const float4*)(kp + 32);
      float4 f11 = *(const float4*)(kp + 36);
      afr0 = pack8(f00, f01);
      afr1 = pack8(f10, f11);
    } else {
      for (int i = 0; i < 8; i++) { afr0[i] = 0; afr1[i] = 0; }
    }
    f32x4 acc[5];
    for (int nt = 0; nt < 5; nt++) {
      f32x4 c = {0.f, 0.f, 0.f, 0.f};
      c = __builtin_amdgcn_mfma_f32_16x16x32_bf16(
          afr0, *(const bf16x8*)&wq_l[nt * 16 + cq][kg * 8], c, 0, 0, 0);
      c = __builtin_amdgcn_mfma_f32_16x16x32_bf16(
          afr1, *(const bf16x8*)&wq_l[nt * 16 + cq][32 + kg * 8], c, 0, 0, 0);
      acc[nt] = c;
    }
    int rbase = mt * 16 + kg * 4;
    for (int nt = 0; nt < 5; nt++) {
      int j = nt * 16 + cq;
      float qp = qpb[j];
      for (int r = 0; r < 4; r++) {
        h1_l[rbase + r][j] = f2b(fmaxf(acc[nt][r] + qp, 0.f));
      }
    }
  }
  __syncthreads();

  // ---------------- GEMM2 + scores ----------------
  float bf0 = bfp[0];
  for (int mt = wave; mt < 13; mt += 4) {
    f32x4 acc[3];
    for (int nt = 0; nt < 3; nt++) acc[nt] = f32x4{0.f, 0.f, 0.f, 0.f};
    for (int kk = 0; kk < 3; kk++) {   // K = 96 (pad zeros beyond 80)
      bf16x8 a2 = *(const bf16x8*)&h1_l[mt * 16 + cq][kk * 32 + kg * 8];
      for (int nt = 0; nt < 3; nt++) {
        acc[nt] = __builtin_amdgcn_mfma_f32_16x16x32_bf16(
            a2, *(const bf16x8*)&w2_l[nt * 16 + cq][kk * 32 + kg * 8], acc[nt], 0, 0, 0);
      }
    }
    float sp0 = 0.f, sp1 = 0.f, sp2 = 0.f, sp3 = 0.f;
    for (int nt = 0; nt < 3; nt++) {
      int g = nt * 16 + cq;
      if (g < 40) {
        float wf = wfl[g], bb = b2l[g];
        sp0 += fmaxf(acc[nt][0] + bb, 0.f) * wf;
        sp1 += fmaxf(acc[nt][1] + bb, 0.f) * wf;
        sp2 += fmaxf(acc[nt][2] + bb, 0.f) * wf;
        sp3 += fmaxf(acc[nt][3] + bb, 0.f) * wf;
      }
    }
    for (int off = 1; off < 16; off <<= 1) {
      sp0 += __shfl_xor(sp0, off);
      sp1 += __shfl_xor(sp1, off);
      sp2 += __shfl_xor(sp2, off);
      sp3 += __shfl_xor(sp3, off);
    }
    if (cq == 0) {
      int t0 = mt * 16 + kg * 4;
      if (t0 < 200) {
        sco[t0 + 0] = sp0 + bf0;
        sco[t0 + 1] = sp1 + bf0;
        sco[t0 + 2] = sp2 + bf0;
        sco[t0 + 3] = sp3 + bf0;
      }
    }
  }
  __syncthreads();

  // ---------------- masked softmax over T (reference numerics) ----------------
  float my = -INFINITY;
  if (tid < 200) {
    float s = sco[tid];
    if (mask[(long)b * 200 + tid] == 0) s = NEG_BIG;
    my = s;
  }
  float m = my;
  for (int off = 32; off; off >>= 1) m = fmaxf(m, __shfl_xor(m, off));
  if (lane == 0) red[wave] = m;
  __syncthreads();
  float mx = fmaxf(fmaxf(red[0], red[1]), fmaxf(red[2], red[3]));
  float e = (tid < 200) ? __expf(my - mx) : 0.f;
  float se = e;
  for (int off = 32; off; off >>= 1) se += __shfl_xor(se, off);
  if (lane == 0) red[4 + wave] = se;
  __syncthreads();
  float tot = red[4] + red[5] + red[6] + red[7];
  if (tid < 200) att[tid] = e / tot;
  __syncthreads();

  // ---------------- weighted sum over v ----------------
  int d = tid & 63, c = tid >> 6;
  float o = 0.f;
  const float* vp = v + (long)b * 12800 + d;
  for (int i = 0; i < 50; i++) {
    int t = i * 4 + c;
    o += att[t] * vp[t * 64];
  }
  op[c][d] = o;
  __syncthreads();
  if (tid < 64) out[b * 64 + tid] = op[0][tid] + op[1][tid] + op[2][tid] + op[3][tid];
}

extern "C" void kernel_launch(void* const* d_in, const int* in_sizes, int n_in,
                              void* d_out, int out_size, void* d_ws, size_t ws_size,
                              hipStream_t stream) {
  const float* q  = (const float*)d_in[0];
  const float* k  = (const float*)d_in[1];
  const float* v  = (const float*)d_in[2];
  const int* mask = (const int*)d_in[3];
  const float* W1 = (const float*)d_in[4];
  const float* b1 = (const float*)d_in[5];
  const float* W2 = (const float*)d_in[6];
  const float* b2 = (const float*)d_in[7];
  const float* Wf = (const float*)d_in[8];
  const float* bf = (const float*)d_in[9];
  float* out = (float*)d_out;

  float* w1qT = (float*)d_ws;            // [80][64] fp32
  float* wkT  = w1qT + 5120;             // [80][64] fp32
  float* wdT  = wkT + 5120;              // [80][64] fp32
  unsigned short* w2t = (unsigned short*)(wdT + 5120);  // [48][104] bf16

  prep_kernel<<<20, 256, 0, stream>>>(W1, W2, w1qT, wkT, wdT, w2t);
  din_kernel<<<4096, 256, 0, stream>>>(q, k, v, mask, b1, b2, Wf, bf,
                                       w1qT, wkT, wdT, w2t, out);
}